// Round 8
// baseline (216.648 us; speedup 1.0000x reference)
//
#include <hip/hip_runtime.h>

#define BB 2
#define TT 2048
#define CC 768
#define HH 12
#define DD 64
#define TBT (BB * TT)   // 4096 rows

typedef __bf16 bfx8 __attribute__((ext_vector_type(8)));
typedef float f32x4 __attribute__((ext_vector_type(4)));
typedef float f32x16 __attribute__((ext_vector_type(16)));

__device__ __forceinline__ unsigned short f2b(float f) {
  unsigned u = __float_as_uint(f);
  return (unsigned short)((u + 0x7FFFu + ((u >> 16) & 1u)) >> 16);
}
__device__ __forceinline__ float b2f(unsigned short u) {
  return __uint_as_float(((unsigned)u) << 16);
}

__device__ __forceinline__ unsigned pack2bf(float lo, float hi) {
  union { __bf16 h[2]; unsigned u; } x;
  x.h[0] = (__bf16)lo; x.h[1] = (__bf16)hi;
  return x.u;   // compiler emits v_cvt_pk_bf16_f32
}

__device__ __forceinline__ void gload_lds16(const void* g, void* l) {
  __builtin_amdgcn_global_load_lds((const __attribute__((address_space(1))) void*)g,
                                   (__attribute__((address_space(3))) void*)l, 16, 0, 0);
}

// ---------------- f32 -> bf16 elementwise (vectorized) ----------------
__global__ __launch_bounds__(256) void k_f32_to_bf16(const float* __restrict__ in,
                                                     unsigned short* __restrict__ out, int n) {
  int i = (blockIdx.x * 256 + threadIdx.x) * 4;
  if (i + 3 < n) {
    float4 v = *(const float4*)(in + i);
    ushort4 o;
    o.x = f2b(v.x); o.y = f2b(v.y); o.z = f2b(v.z); o.w = f2b(v.w);
    *(ushort4*)(out + i) = o;
  }
}

// ---------------- W [K,N] f32  ->  WT [N,K] bf16 (LDS tiled) ----------------
__global__ __launch_bounds__(256) void k_transpose_w(const float* __restrict__ W,
                                                     unsigned short* __restrict__ WT,
                                                     int K, int N) {
  __shared__ float tile[32][33];
  int n0 = blockIdx.x * 32, k0 = blockIdx.y * 32;
  int j = threadIdx.x & 31, i0 = threadIdx.x >> 5;
  for (int i = i0; i < 32; i += 8) tile[i][j] = W[(size_t)(k0 + i) * N + n0 + j];
  __syncthreads();
  for (int i = i0; i < 32; i += 8) WT[(size_t)(n0 + i) * K + k0 + j] = f2b(tile[j][i]);
}

// ---------------- GEMM: C[M,N] = A[M,K] @ B[K,N],  Bt given as [N,K] ----------------
// MODE 0: out = bf16(acc + bias)
// MODE 1: out = bf16(gelu(acc + bias))        (exact erf gelu)
// MODE 3: split-K over blockIdx.z (2 halves): raw f32 partial (no bias) -> outf0/outf1
template<int MODE>
__global__ __launch_bounds__(256) void k_gemm_bt(const unsigned short* __restrict__ A,
                                                 const unsigned short* __restrict__ Bt,
                                                 const float* __restrict__ bias,
                                                 unsigned short* __restrict__ outb,
                                                 float* __restrict__ outf0,
                                                 float* __restrict__ outf1,
                                                 int M, int N, int K) {
  __shared__ __align__(16) unsigned short As[128 * 64];
  __shared__ __align__(16) unsigned short Bs[128 * 64];
  const int tid = threadIdx.x;
  const int l = tid & 63, w = tid >> 6;
  const int wr = w >> 1, wc = w & 1;
  const int lr = l & 15, g = l >> 4;

  // bijective XCD-chunked swizzle over (x,y) (nwg % 8 == 0 for all our grids)
  const int gx = gridDim.x, nwg = gx * gridDim.y;
  const int orig = blockIdx.x + gx * blockIdx.y;
  const int q8 = nwg >> 3;
  const int swz = (orig & 7) * q8 + (orig >> 3);
  const int m0 = (swz / gx) * 128, n0 = (swz % gx) * 128;

  int kbeg = 0, kend = K;
  if (MODE == 3) { int K2 = K >> 1; kbeg = blockIdx.z * K2; kend = kbeg + K2; }

  f32x4 acc[4][4] = {};

  for (int kt = kbeg; kt < kend; kt += 64) {
#pragma unroll
    for (int i = 0; i < 4; ++i) {
      int s = tid + i * 256;           // 16B slot index, 0..1023
      int row = s >> 3;
      int q = (s & 7) ^ (row & 7);     // inverse-swizzled global source (linear LDS dest)
      gload_lds16(A + (size_t)(m0 + row) * K + kt + q * 8, &As[s * 8]);
      gload_lds16(Bt + (size_t)(n0 + row) * K + kt + q * 8, &Bs[s * 8]);
    }
    __syncthreads();
#pragma unroll
    for (int kk = 0; kk < 2; ++kk) {
      bfx8 af[4], bfr[4];
#pragma unroll
      for (int m = 0; m < 4; ++m) {
        int row = wr * 64 + m * 16 + lr;
        int quad = (kk * 4 + g) ^ (row & 7);
        af[m] = *(const bfx8*)(&As[row * 64 + quad * 8]);
      }
#pragma unroll
      for (int n = 0; n < 4; ++n) {
        int row = wc * 64 + n * 16 + lr;
        int quad = (kk * 4 + g) ^ (row & 7);
        bfr[n] = *(const bfx8*)(&Bs[row * 64 + quad * 8]);
      }
#pragma unroll
      for (int m = 0; m < 4; ++m)
#pragma unroll
        for (int n = 0; n < 4; ++n)
          acc[m][n] = __builtin_amdgcn_mfma_f32_16x16x32_bf16(af[m], bfr[n], acc[m][n], 0, 0, 0);
    }
    __syncthreads();
  }

  float* dst = (MODE == 3) ? (blockIdx.z ? outf1 : outf0) : nullptr;
#pragma unroll
  for (int m = 0; m < 4; ++m) {
#pragma unroll
    for (int n = 0; n < 4; ++n) {
      int col = n0 + wc * 64 + n * 16 + lr;
      float bv = (MODE == 3) ? 0.f : bias[col];
#pragma unroll
      for (int r = 0; r < 4; ++r) {
        int row = m0 + wr * 64 + m * 16 + g * 4 + r;
        float v = acc[m][n][r] + bv;
        if (MODE == 1) v = 0.5f * v * (1.0f + erff(v * 0.70710678118654752440f));
        if (MODE == 3) {
          dst[(size_t)row * N + col] = v;
        } else {
          outb[(size_t)row * N + col] = f2b(v);
        }
      }
    }
  }
}

// ---------------- V transpose (LDS tiled): qkv bf16 -> VT[b,h,d,t] bf16 ----------------
__global__ __launch_bounds__(256) void k_vtrans(const unsigned short* __restrict__ qkv,
                                                unsigned short* __restrict__ VT) {
  __shared__ unsigned short tile[32][33];
  int t0 = blockIdx.x * 32, d0 = blockIdx.y * 32, bh = blockIdx.z;
  int b = bh / HH, h = bh % HH;
  int j = threadIdx.x & 31, i0 = threadIdx.x >> 5;
  for (int i = i0; i < 32; i += 8)
    tile[i][j] = qkv[(size_t)(b * TT + t0 + i) * (3 * CC) + 2 * CC + h * DD + d0 + j];
  __syncthreads();
  for (int i = i0; i < 32; i += 8)
    VT[((size_t)(bh * DD + d0 + i)) * TT + t0 + j] = tile[j][i];
}

// ---------------- causal flash attention pass 1 (work-uniform k-chunks of <=4 tiles) ------
// Each (bh, q-block bx) causal range of nt=2bx+2 tiles is cut into chunks of <=4 tiles.
// 72 chunks per bh -> grid (72, 24), work in {2,4} tiles. Single-chunk q-blocks (bx<2)
// write normalized output directly; multi-chunk write unnormalized bf16 O-partial + (m,l).
__global__ __launch_bounds__(256) void k_attn(const unsigned short* __restrict__ qkv,
                                              const unsigned short* __restrict__ VT,
                                              unsigned short* __restrict__ aout,
                                              unsigned short* __restrict__ opart0,
                                              unsigned short* __restrict__ opart1,
                                              float2* __restrict__ ml) {
  __shared__ __align__(16) unsigned short Ks[2][64 * 64];
  __shared__ __align__(16) unsigned short Vs[2][64 * 64];
  const int tid = threadIdx.x;
  const int l = tid & 63, w = tid >> 6;
  const int ql = l & 31, hi = l >> 5;
  const int bh = blockIdx.y;
  const int b = bh / HH, h = bh % HH;

  // decode chunk id -> (bx, sub): bx has (bx+2)>>1 chunks (sizes 4,...,4[,2])
  int bx = 0, sub = blockIdx.x;
  while (sub >= ((bx + 2) >> 1)) { sub -= (bx + 2) >> 1; ++bx; }
  const int nt = 2 * bx + 2;
  const int nchunks = (bx + 2) >> 1;
  const int t0i = sub * 4;
  const int tcount = min(4, nt - t0i);

  const int qw = bx * 128 + w * 32;    // this wave's 32 q-rows
  const int qrow = qw + ql;

  const unsigned short* Kbase = qkv + (size_t)(b * TT) * (3 * CC) + CC + h * DD;
  const unsigned short* Vbase = VT + (size_t)bh * DD * TT;

  // Q as B-operand frags, pre-scaled to log2 domain
  bfx8 qf[4];
  {
    const unsigned short* qp = qkv + (size_t)(b * TT + qrow) * (3 * CC) + h * DD;
    const float SC = 0.125f * 1.44269504088896340736f;
#pragma unroll
    for (int c = 0; c < 4; ++c) {
      bfx8 rw = *(const bfx8*)(qp + c * 16 + hi * 8);
#pragma unroll
      for (int j = 0; j < 8; ++j) qf[c][j] = (__bf16)((float)rw[j] * SC);
    }
  }

  f32x16 o0 = {}, o1 = {};
  float m_run = -1e30f, l_run = 0.f;

  auto stage = [&](int t, int bufi) {
    const int k0 = t * 64;
#pragma unroll
    for (int i = 0; i < 2; ++i) {
      int sl = tid + i * 256;
      int row = sl >> 3;
      int q = (sl & 7) ^ (row & 7);
      gload_lds16(Kbase + (size_t)(k0 + row) * (3 * CC) + q * 8, &Ks[bufi][sl * 8]);
      gload_lds16(Vbase + (size_t)row * TT + k0 + q * 8, &Vs[bufi][sl * 8]);
    }
  };

  stage(t0i, 0);
  __syncthreads();

  int cur = 0;
  for (int ti = 0; ti < tcount; ++ti) {
    const int t = t0i + ti;
    const int k0 = t * 64;
    if (ti + 1 < tcount) stage(t + 1, cur ^ 1);

    if (k0 <= qw + 31) {   // wave-uniform: skip fully-masked tiles
      f32x16 sa[2];
      __builtin_amdgcn_s_setprio(1);
#pragma unroll
      for (int kh = 0; kh < 2; ++kh) {
        f32x16 acc = {};
        int row = kh * 32 + ql;
        int rx = row & 7;
#pragma unroll
        for (int c = 0; c < 4; ++c) {
          int quad = (c * 2 + hi) ^ rx;
          bfx8 kf = *(const bfx8*)(&Ks[cur][row * 64 + quad * 8]);
          acc = __builtin_amdgcn_mfma_f32_32x32x16_bf16(kf, qf[c], acc, 0, 0, 0);
        }
        sa[kh] = acc;
      }
      __builtin_amdgcn_s_setprio(0);

      if (k0 + 63 > qw) {   // diagonal-region mask
#pragma unroll
        for (int kh = 0; kh < 2; ++kh)
#pragma unroll
          for (int r = 0; r < 16; ++r) {
            int kk = k0 + kh * 32 + (r & 3) + 8 * (r >> 2) + 4 * hi;
            if (kk > qrow) sa[kh][r] = -1e30f;
          }
      }

      // ---- row max: depth-5 tree + cross-half shfl ----
      float m8[8];
#pragma unroll
      for (int r = 0; r < 8; ++r)
        m8[r] = fmaxf(fmaxf(sa[0][r], sa[0][r + 8]), fmaxf(sa[1][r], sa[1][r + 8]));
      float ma = fmaxf(m8[0], m8[4]), mb = fmaxf(m8[1], m8[5]);
      float mc = fmaxf(m8[2], m8[6]), md = fmaxf(m8[3], m8[7]);
      float mx = fmaxf(fmaxf(ma, mb), fmaxf(mc, md));
      mx = fmaxf(mx, __shfl_xor(mx, 32));

      // ---- defer-max rescale (log2 domain) ----
      if (__any(mx > m_run + 11.0f)) {
        float mn = fmaxf(m_run, mx);
        float al = __builtin_amdgcn_exp2f(m_run - mn);
        m_run = mn;
        l_run *= al;
        o0 *= al;
        o1 *= al;
      }

      // ---- p = exp2(s - m), 4 independent sum chains, pack to bf16 pairs ----
      float rs0 = 0.f, rs1 = 0.f, rs2 = 0.f, rs3 = 0.f;
      unsigned pk[2][8];
#pragma unroll
      for (int kh = 0; kh < 2; ++kh)
#pragma unroll
        for (int i = 0; i < 8; ++i) {
          float p0 = __builtin_amdgcn_exp2f(sa[kh][2 * i] - m_run);
          float p1 = __builtin_amdgcn_exp2f(sa[kh][2 * i + 1] - m_run);
          float ps = p0 + p1;
          if ((i & 3) == 0) rs0 += ps;
          else if ((i & 3) == 1) rs1 += ps;
          else if ((i & 3) == 2) rs2 += ps;
          else rs3 += ps;
          pk[kh][i] = pack2bf(p0, p1);
        }
      float rs = (rs0 + rs1) + (rs2 + rs3);
      rs += __shfl_xor(rs, 32);
      l_run += rs;

      // ---- in-register P^T -> B-frags via permlane32_swap ----
      bfx8 pf[4];
#pragma unroll
      for (int kh = 0; kh < 2; ++kh)
#pragma unroll
        for (int c = 0; c < 2; ++c) {
          unsigned a0 = pk[kh][c * 4 + 0], a1 = pk[kh][c * 4 + 1];
          unsigned b0 = pk[kh][c * 4 + 2], b1 = pk[kh][c * 4 + 3];
          asm volatile("v_permlane32_swap_b32 %0, %1" : "+v"(a0), "+v"(b0));
          asm volatile("v_permlane32_swap_b32 %0, %1" : "+v"(a1), "+v"(b1));
          union { unsigned u[4]; bfx8 v; } cvt;
          cvt.u[0] = a0; cvt.u[1] = a1; cvt.u[2] = b0; cvt.u[3] = b1;
          pf[kh * 2 + c] = cvt.v;
        }

      __builtin_amdgcn_s_setprio(1);
#pragma unroll
      for (int kc = 0; kc < 4; ++kc) {
        {
          int row = ql;
          bfx8 vf = *(const bfx8*)(&Vs[cur][row * 64 + (((kc * 2 + hi) ^ (row & 7)) * 8)]);
          o0 = __builtin_amdgcn_mfma_f32_32x32x16_bf16(vf, pf[kc], o0, 0, 0, 0);
        }
        {
          int row = 32 + ql;
          bfx8 vf = *(const bfx8*)(&Vs[cur][row * 64 + (((kc * 2 + hi) ^ (row & 7)) * 8)]);
          o1 = __builtin_amdgcn_mfma_f32_32x32x16_bf16(vf, pf[kc], o1, 0, 0, 0);
        }
      }
      __builtin_amdgcn_s_setprio(0);
    }

    __syncthreads();
    cur ^= 1;
  }

  if (nchunks == 1) {
    // single chunk covers the whole causal range: write normalized output directly
    float inv = 1.0f / l_run;
    unsigned short* orow = aout + (size_t)(b * TT + qrow) * CC + h * DD;
#pragma unroll
    for (int dh = 0; dh < 2; ++dh) {
      const f32x16& oo = dh ? o1 : o0;
#pragma unroll
      for (int qd = 0; qd < 4; ++qd) {
        ushort4 v;
        v.x = f2b(oo[qd * 4 + 0] * inv);
        v.y = f2b(oo[qd * 4 + 1] * inv);
        v.z = f2b(oo[qd * 4 + 2] * inv);
        v.w = f2b(oo[qd * 4 + 3] * inv);
        *(ushort4*)(orow + dh * 32 + 8 * qd + 4 * hi) = v;
      }
    }
  } else {
    const size_t S = (size_t)TBT * CC;
    unsigned short* obase = (sub < 4) ? (opart0 + (size_t)sub * S)
                                      : (opart1 + (size_t)(sub - 4) * S);
    unsigned short* orow = obase + (size_t)(b * TT + qrow) * CC + h * DD;
#pragma unroll
    for (int dh = 0; dh < 2; ++dh) {
      const f32x16& oo = dh ? o1 : o0;
#pragma unroll
      for (int qd = 0; qd < 4; ++qd) {
        ushort4 v;
        v.x = f2b(oo[qd * 4 + 0]);
        v.y = f2b(oo[qd * 4 + 1]);
        v.z = f2b(oo[qd * 4 + 2]);
        v.w = f2b(oo[qd * 4 + 3]);
        *(ushort4*)(orow + dh * 32 + 8 * qd + 4 * hi) = v;
      }
    }
    if (hi == 0) ml[((size_t)sub * (BB * HH) + bh) * TT + qrow] = make_float2(m_run, l_run);
  }
}

// ---------------- attention combine: merge up to 8 unnormalized partials ----------------
__global__ __launch_bounds__(256) void k_attn_combine(const unsigned short* __restrict__ op0,
                                                      const unsigned short* __restrict__ op1,
                                                      const float2* __restrict__ ml,
                                                      unsigned short* __restrict__ aout) {
  int idx = (blockIdx.x * 256 + threadIdx.x) * 4;
  int bt = idx / CC, c = idx % CC;
  int b = bt >> 11, t = bt & (TT - 1);
  int bx = t >> 7;
  int cnt = (bx + 2) >> 1;
  if (cnt < 2) return;                       // single-chunk rows written by pass 1
  int h = c >> 6;
  int bh = b * HH + h;

  float2 mls[8];
  float M = -1e30f;
#pragma unroll
  for (int s = 0; s < 8; ++s) {
    mls[s] = make_float2(-1e30f, 0.f);
    if (s < cnt) { mls[s] = ml[((size_t)s * (BB * HH) + bh) * TT + t]; M = fmaxf(M, mls[s].x); }
  }
  float ww[8], lsum = 0.f;
#pragma unroll
  for (int s = 0; s < 8; ++s) {
    ww[s] = (s < cnt) ? __builtin_amdgcn_exp2f(mls[s].x - M) : 0.f;
    lsum += ww[s] * mls[s].y;
  }
  float linv = 1.0f / lsum;

  const size_t S = (size_t)TBT * CC;
  float a0 = 0.f, a1 = 0.f, a2 = 0.f, a3 = 0.f;
#pragma unroll
  for (int s = 0; s < 8; ++s)
    if (s < cnt) {
      const unsigned short* base = (s < 4) ? (op0 + (size_t)s * S) : (op1 + (size_t)(s - 4) * S);
      ushort4 v = *(const ushort4*)(base + idx);
      a0 += b2f(v.x) * ww[s];
      a1 += b2f(v.y) * ww[s];
      a2 += b2f(v.z) * ww[s];
      a3 += b2f(v.w) * ww[s];
    }
  ushort4 o;
  o.x = f2b(a0 * linv);
  o.y = f2b(a1 * linv);
  o.z = f2b(a2 * linv);
  o.w = f2b(a3 * linv);
  *(ushort4*)(aout + idx) = o;
}

// ---------------- LayerNorm+combine over C=768: v = in0+in1+resid+bias, then LN ----------------
template<int WF32, int WB16>
__global__ __launch_bounds__(256) void k_layernorm_c(const float* __restrict__ in0,
                                                     const float* __restrict__ in1,
                                                     const float* __restrict__ resid,
                                                     const float* __restrict__ biasv,
                                                     const float* __restrict__ gw,
                                                     const float* __restrict__ bw,
                                                     float* __restrict__ outf,
                                                     unsigned short* __restrict__ outb) {
  __shared__ float red[8];
  const int row = blockIdx.x;
  const int tid = threadIdx.x;
  float v[3];
  float s = 0.f;
#pragma unroll
  for (int j = 0; j < 3; ++j) {
    int c = tid + j * 256;
    size_t idx = (size_t)row * CC + c;
    v[j] = in0[idx] + in1[idx] + resid[idx] + biasv[c];
    s += v[j];
  }
#pragma unroll
  for (int off = 32; off; off >>= 1) s += __shfl_xor(s, off);
  if ((tid & 63) == 0) red[tid >> 6] = s;
  __syncthreads();
  s = red[0] + red[1] + red[2] + red[3];
  float mu = s * (1.0f / CC);
  float qs = 0.f;
#pragma unroll
  for (int j = 0; j < 3; ++j) { float d = v[j] - mu; qs += d * d; }
#pragma unroll
  for (int off = 32; off; off >>= 1) qs += __shfl_xor(qs, off);
  if ((tid & 63) == 0) red[4 + (tid >> 6)] = qs;
  __syncthreads();
  qs = red[4] + red[5] + red[6] + red[7];
  float rstd = rsqrtf(qs * (1.0f / CC) + 1e-5f);
#pragma unroll
  for (int j = 0; j < 3; ++j) {
    int c = tid + j * 256;
    float y = (v[j] - mu) * rstd * gw[c] + bw[c];
    if (WF32) outf[(size_t)row * CC + c] = y;
    if (WB16) outb[(size_t)row * CC + c] = f2b(y);
  }
}

extern "C" void kernel_launch(void* const* d_in, const int* in_sizes, int n_in,
                              void* d_out, int out_size, void* d_ws, size_t ws_size,
                              hipStream_t stream) {
  (void)in_sizes; (void)n_in; (void)out_size; (void)ws_size;
  const float* x    = (const float*)d_in[0];
  const float* Wqkv = (const float*)d_in[1];
  const float* bqkv = (const float*)d_in[2];
  const float* Wo   = (const float*)d_in[3];
  const float* bo   = (const float*)d_in[4];
  const float* ln1g = (const float*)d_in[5];
  const float* ln1b = (const float*)d_in[6];
  const float* Wf   = (const float*)d_in[7];
  const float* bf_  = (const float*)d_in[8];
  const float* Wp   = (const float*)d_in[9];
  const float* bp   = (const float*)d_in[10];
  const float* ln2g = (const float*)d_in[11];
  const float* ln2b = (const float*)d_in[12];

  char* ws = (char*)d_ws;
  size_t off = 0;
  auto alloc = [&](size_t bytes) {
    void* p = ws + off;
    off += (bytes + 255) & ~(size_t)255;
    return p;
  };
  unsigned short* xb    = (unsigned short*)alloc((size_t)TBT * CC * 2);
  unsigned short* WqkvT = (unsigned short*)alloc((size_t)3 * CC * CC * 2);
  unsigned short* WoT   = (unsigned short*)alloc((size_t)CC * CC * 2);
  unsigned short* WfT   = (unsigned short*)alloc((size_t)4 * CC * CC * 2);
  unsigned short* WpT   = (unsigned short*)alloc((size_t)4 * CC * CC * 2);
  unsigned short* qkvb  = (unsigned short*)alloc((size_t)TBT * 3 * CC * 2);
  unsigned short* VTb   = (unsigned short*)alloc((size_t)TBT * CC * 2);
  float*          hbuf  = (float*)alloc((size_t)TBT * CC * 4);
  float*          hln   = (float*)alloc((size_t)TBT * CC * 4);
  unsigned short* hlnb  = (unsigned short*)alloc((size_t)TBT * CC * 2);
  unsigned short* gbuf  = (unsigned short*)alloc((size_t)TBT * 4 * CC * 2);

  // aliases (lifetime-disjoint):
  unsigned short* aout   = xb;                    // attn final out (xb dead after QKV GEMM)
  unsigned short* opart0 = gbuf;                  // attn O-partial subs 0-3 (4 x 6.29MB, gbuf free pre-FFN1)
  unsigned short* opart1 = (unsigned short*)hbuf; // subs 4-7 overlay hbuf+hln (contiguous 25.2MB, free here)
  float2*         mlbuf  = (float2*)hlnb;         // attn (m,l), 8 x 24 x 2048 x 8B = 3.1MB (hlnb free here)
  float*          woP0   = (float*)gbuf;          // Wo split-K partials (opart dead after combine)
  float*          woP1   = (float*)((char*)gbuf + (size_t)TBT * CC * 4);
  float*          fpP0   = hbuf;                  // FFN2 split-K partials (opart1/mlbuf dead by then)
  float*          fpP1   = (float*)qkvb;          // (qkvb dead after attention pass 1)

  k_f32_to_bf16<<<(TBT * CC) / 1024, 256, 0, stream>>>(x, xb, TBT * CC);
  k_transpose_w<<<dim3(3 * CC / 32, CC / 32), 256, 0, stream>>>(Wqkv, WqkvT, CC, 3 * CC);
  k_transpose_w<<<dim3(CC / 32, CC / 32), 256, 0, stream>>>(Wo, WoT, CC, CC);
  k_transpose_w<<<dim3(4 * CC / 32, CC / 32), 256, 0, stream>>>(Wf, WfT, CC, 4 * CC);
  k_transpose_w<<<dim3(CC / 32, 4 * CC / 32), 256, 0, stream>>>(Wp, WpT, 4 * CC, CC);

  // qkv = x @ Wqkv + bqkv   -> bf16 [4096, 2304]
  k_gemm_bt<0><<<dim3(3 * CC / 128, TBT / 128), 256, 0, stream>>>(
      xb, WqkvT, bqkv, qkvb, nullptr, nullptr, TBT, 3 * CC, CC);
  // VT[b,h,d,t]
  k_vtrans<<<dim3(TT / 32, DD / 32, BB * HH), 256, 0, stream>>>(qkvb, VTb);
  // attention pass 1 (72 work-uniform chunks/bh) -> aout (1-chunk rows) + opart/ml
  k_attn<<<dim3(72, BB * HH), 256, 0, stream>>>(qkvb, VTb, aout, opart0, opart1, mlbuf);
  // combine multi-chunk rows -> aout bf16
  k_attn_combine<<<(TBT * CC) / 1024, 256, 0, stream>>>(opart0, opart1, mlbuf, aout);
  // attn @ Wo (split-K=2) -> woP0/woP1 f32 partials
  k_gemm_bt<3><<<dim3(CC / 128, TBT / 128, 2), 256, 0, stream>>>(
      aout, WoT, nullptr, nullptr, woP0, woP1, TBT, CC, CC);
  // LN1( woP0+woP1 + x + bo ) -> hln (f32) + hlnb (bf16)
  k_layernorm_c<1, 1><<<TBT, 256, 0, stream>>>(woP0, woP1, x, bo, ln1g, ln1b, hln, hlnb);
  // g = gelu(hln @ Wf + bf) -> bf16 [4096, 3072]
  k_gemm_bt<1><<<dim3(4 * CC / 128, TBT / 128), 256, 0, stream>>>(
      hlnb, WfT, bf_, gbuf, nullptr, nullptr, TBT, 4 * CC, CC);
  // g @ Wp (split-K=2) -> fpP0/fpP1 f32 partials
  k_gemm_bt<3><<<dim3(CC / 128, TBT / 128, 2), 256, 0, stream>>>(
      gbuf, WpT, nullptr, nullptr, fpP0, fpP1, TBT, CC, 4 * CC);
  // LN2( fpP0+fpP1 + hln + bp ) -> d_out (f32)
  k_layernorm_c<1, 0><<<TBT, 256, 0, stream>>>(fpP0, fpP1, hln, bp, ln2g, ln2b,
                                               (float*)d_out, nullptr);
}